// Round 9
// baseline (4883.371 us; speedup 1.0000x reference)
//
#include <hip/hip_runtime.h>

#define BATCHN 128
#define SEQT   2048
#define FEAT   64
#define UNITS  64
#define NCOL   256   // 4*UNITS gate columns
#define OUTD   6

typedef float v2f __attribute__((ext_vector_type(2)));

__device__ __forceinline__ float fast_exp2(float x) {
#if __has_builtin(__builtin_amdgcn_exp2f)
    return __builtin_amdgcn_exp2f(x);
#else
    return exp2f(x);
#endif
}
__device__ __forceinline__ float fast_rcp(float x) {
#if __has_builtin(__builtin_amdgcn_rcpf)
    return __builtin_amdgcn_rcpf(x);
#else
    return 1.0f / x;
#endif
}
__device__ __forceinline__ float sig_(float x) {
    return fast_rcp(1.0f + fast_exp2(-1.4426950408889634f * x));
}
__device__ __forceinline__ float tanh_(float x) {
    float xc = fminf(fmaxf(x, -15.0f), 15.0f);
    float e  = fast_exp2(2.8853900817779268f * xc);  // e^(2x)
    return (e - 1.0f) * fast_rcp(e + 1.0f);
}

__device__ __forceinline__ v2f pk_fma(v2f a, v2f b, v2f c) {
    return __builtin_elementwise_fma(a, b, c);
}

// wave-uniform broadcast of lane `l`'s value (result lands in an SGPR)
__device__ __forceinline__ float rl_(float v, int l) {
    return __builtin_bit_cast(float,
        __builtin_amdgcn_readlane(__builtin_bit_cast(int, v), l));
}

// 6 waves: wid = 2*layer + role; role 0 = FF (z_ff = in @ W + b),
// role 1 = REC (z = z_ff + h_prev @ U, activations, state update).
// Lane u owns unit u's 4 gate columns over the full K=64 of its matrix:
// dot products complete IN-LANE (no cross-lane reduce). Operand values are
// broadcast per-k with v_readlane (REC: own h register; FF: 1 LDS b32 read).
// 6-stage skew (alpha = 2g+r): every dependency is previous-tick.
__global__ __launch_bounds__(384, 1)
void lstm3_rl(const float* __restrict__ x,
              const float* __restrict__ W0, const float* __restrict__ U0,
              const float* __restrict__ b0,
              const float* __restrict__ W1, const float* __restrict__ U1,
              const float* __restrict__ b1,
              const float* __restrict__ Wf, const float* __restrict__ bfv,
              const float* __restrict__ Wo, const float* __restrict__ bov,
              float* __restrict__ out)
{
    const int b   = blockIdx.x;
    const int tid = threadIdx.x;   // 0..383
    const int wid = tid >> 6;      // 0..5
    const int g   = wid >> 1;      // layer 0,1,2
    const int r   = wid & 1;       // 0=FF, 1=REC
    const int u   = tid & 63;      // unit / lane

    __shared__ __align__(16) float lzff[3][2][4 * UNITS];  // FF partials (i,f,g,o per unit)
    __shared__ __align__(16) float lh[3][2][UNITS];        // h per layer, per parity
    __shared__ float lact[UNITS];

    // ---- weights: 4 gate cols of unit u x 64 k of ONE matrix = 128 v2f ----
    const float* M = (g == 0) ? ((r == 0) ? W0 : U0)
                              : ((r == 0) ? W1 : U1);
    v2f wif[64], wgo[64];
#pragma unroll
    for (int k = 0; k < 64; ++k) {
        wif[k] = (v2f){M[k * NCOL +       u], M[k * NCOL +  64 + u]};
        wgo[k] = (v2f){M[k * NCOL + 128 + u], M[k * NCOL + 192 + u]};
    }
    const float* bsel = (g == 0) ? b0 : b1;
    const v2f bif = (v2f){bsel[u],       bsel[ 64 + u]};
    const v2f bgo = (v2f){bsel[128 + u], bsel[192 + u]};

    // zero LDS
    for (int i = tid; i < 3 * 2 * 4 * UNITS; i += 384) ((float*)lzff)[i] = 0.f;
    for (int i = tid; i < 3 * 2 * UNITS;     i += 384) ((float*)lh)[i]   = 0.f;

    // x: G0-FF wave lane u streams x[t][u]; depth-2 register prefetch
    const float* xrow = x + (size_t)b * SEQT * FEAT + u;
    const bool isX = (wid == 0);
    float xr0 = 0.f, xr1 = 0.f;
    if (isX) { xr0 = xrow[0]; xr1 = xrow[FEAT]; }   // x(0), x(1)
    __syncthreads();

    const int alpha = 2 * g + r;   // my pipeline offset
    float hreg = 0.f, creg = 0.f;

#define TICK(TK, XR)                                                          \
    {                                                                         \
        const int p_ = (TK) & 1;                                              \
        const int t_ = (TK) - alpha;                                          \
        const float xcur = (XR);                                              \
        if (isX) {            /* issue x(TK+2); lands well before use */      \
            int tn = (TK) + 2; if (tn > SEQT - 1) tn = SEQT - 1;              \
            (XR) = xrow[(size_t)tn * FEAT];                                   \
        }                                                                     \
        if (t_ >= 0 && t_ < SEQT) {                                           \
            float src;                                                        \
            if (r == 0) src = (g == 0) ? xcur : lh[g - 1][p_ ^ 1][u];         \
            else        src = hreg;   /* own h(t-1), in-lane */               \
            v2f aifA = (r == 0) ? bif : (v2f){0.f, 0.f};                      \
            v2f agoA = (r == 0) ? bgo : (v2f){0.f, 0.f};                      \
            v2f aifB = (v2f){0.f, 0.f}, agoB = (v2f){0.f, 0.f};               \
            _Pragma("unroll")                                                 \
            for (int k = 0; k < 64; k += 2) {                                 \
                const float h0 = rl_(src, k);                                 \
                const float h1 = rl_(src, k + 1);                             \
                const v2f hv0 = (v2f){h0, h0};                                \
                const v2f hv1 = (v2f){h1, h1};                                \
                aifA = pk_fma(hv0, wif[k],     aifA);                         \
                agoA = pk_fma(hv0, wgo[k],     agoA);                         \
                aifB = pk_fma(hv1, wif[k + 1], aifB);                         \
                agoB = pk_fma(hv1, wgo[k + 1], agoB);                         \
            }                                                                 \
            const v2f aif = aifA + aifB;                                      \
            const v2f ago = agoA + agoB;                                      \
            if (r == 0) {                                                     \
                float4 z4 = {aif.x, aif.y, ago.x, ago.y};                     \
                *(float4*)&lzff[g][p_][4 * u] = z4;                           \
            } else {                                                          \
                float4 z4 = *(const float4*)&lzff[g][p_ ^ 1][4 * u];          \
                const float zi = z4.x + aif.x, zf = z4.y + aif.y;             \
                const float zg = z4.z + ago.x, zo = z4.w + ago.y;             \
                const float pi = sig_(zi), pf = sig_(zf);                     \
                const float pg = tanh_(zg), po = sig_(zo);                    \
                creg = pf * creg + pi * pg;                                   \
                hreg = po * tanh_(creg);                                      \
                lh[g][p_][u] = hreg;                                          \
            }                                                                 \
        }                                                                     \
        __syncthreads();                                                      \
    }

    // SEQT+6 ticks (even count for the 2-step unroll; last tick is idle)
    for (int tk = 0; tk < SEQT + 6; tk += 2) {
        TICK(tk,     xr0)
        TICK(tk + 1, xr1)
    }
#undef TICK

    // ---- dense head: final h2 = step SEQT-1, written at tick SEQT+4 (p=0) --
    const float* h2f = lh[2][0];
    if (tid < UNITS) {
        float a = bfv[tid];
#pragma unroll
        for (int k = 0; k < UNITS; ++k) a += h2f[k] * Wf[k * 64 + tid];
        lact[tid] = fmaxf(a, 0.f);
    }
    __syncthreads();
    if (tid < OUTD) {
        float a = bov[tid];
#pragma unroll
        for (int k = 0; k < UNITS; ++k) a += lact[k] * Wo[k * OUTD + tid];
        out[b * OUTD + tid] = a;
    }
}

extern "C" void kernel_launch(void* const* d_in, const int* in_sizes, int n_in,
                              void* d_out, int out_size, void* d_ws, size_t ws_size,
                              hipStream_t stream) {
    const float* x   = (const float*)d_in[0];
    const float* W0  = (const float*)d_in[1];
    const float* U0  = (const float*)d_in[2];
    const float* b0  = (const float*)d_in[3];
    const float* W1  = (const float*)d_in[4];
    const float* U1  = (const float*)d_in[5];
    const float* b1  = (const float*)d_in[6];
    const float* Wf  = (const float*)d_in[7];
    const float* bfv = (const float*)d_in[8];
    const float* Wo  = (const float*)d_in[9];
    const float* bov = (const float*)d_in[10];
    float* out = (float*)d_out;

    lstm3_rl<<<BATCHN, 384, 0, stream>>>(x, W0, U0, b0, W1, U1, b1,
                                         Wf, bfv, Wo, bov, out);
}

// Round 10
// 2138.270 us; speedup vs baseline: 2.2838x; 2.2838x over previous
//
#include <hip/hip_runtime.h>

#define BATCHN 128
#define SEQT   2048
#define FEAT   64
#define UNITS  64
#define NCOL   256   // 4*UNITS gate columns
#define OUTD   6
#define CH     24    // lh chunk stride in floats (16 data + 8 pad)
#define BUF    96    // lh buffer stride (4*CH)
#define RING   8     // x ring depth (slots of 64 floats)
#define PFD    6     // x prefetch distance in ticks

typedef float v2f __attribute__((ext_vector_type(2)));

__device__ __forceinline__ float fast_exp2(float x) {
#if __has_builtin(__builtin_amdgcn_exp2f)
    return __builtin_amdgcn_exp2f(x);
#else
    return exp2f(x);
#endif
}
__device__ __forceinline__ float fast_rcp(float x) {
#if __has_builtin(__builtin_amdgcn_rcpf)
    return __builtin_amdgcn_rcpf(x);
#else
    return 1.0f / x;
#endif
}
__device__ __forceinline__ float sig_(float x) {
    return fast_rcp(1.0f + fast_exp2(-1.4426950408889634f * x));
}
__device__ __forceinline__ float tanh_(float x) {
    float xc = fminf(fmaxf(x, -15.0f), 15.0f);
    float e  = fast_exp2(2.8853900817779268f * xc);  // e^(2x)
    return (e - 1.0f) * fast_rcp(e + 1.0f);
}

__device__ __forceinline__ v2f pk_fma(v2f a, v2f b, v2f c) {
    return __builtin_elementwise_fma(a, b, c);
}

template<int CTRL>
__device__ __forceinline__ float dppf(float v) {
    return __builtin_bit_cast(float, __builtin_amdgcn_update_dpp(
        0, __builtin_bit_cast(int, v), CTRL, 0xF, 0xF, true));
}
// reduce both v2f components across 8 consecutive lanes (bits [2:0])
__device__ __forceinline__ v2f red8v(v2f v) {
    v2f t;
    t.x = dppf<0xB1>(v.x);  t.y = dppf<0xB1>(v.y);  v = v + t;  // xor 1
    t.x = dppf<0x4E>(v.x);  t.y = dppf<0x4E>(v.y);  v = v + t;  // xor 2
    t.x = dppf<0x141>(v.x); t.y = dppf<0x141>(v.y); v = v + t;  // xor 4 (RHM)
    return v;
}

// async global->LDS DMA, 16B per active lane; LDS dest = uniform base + lane*16
__device__ __forceinline__ void gload16(float* lds, const float* g) {
    __builtin_amdgcn_global_load_lds(
        (const __attribute__((address_space(1))) void*)g,
        (__attribute__((address_space(3))) void*)lds, 16, 0, 0);
}

__global__ __launch_bounds__(768, 3)
void lstm3_ring(const float* __restrict__ x,
                const float* __restrict__ W0, const float* __restrict__ U0,
                const float* __restrict__ b0,
                const float* __restrict__ W1, const float* __restrict__ U1,
                const float* __restrict__ b1,
                const float* __restrict__ Wf, const float* __restrict__ bfv,
                const float* __restrict__ Wo, const float* __restrict__ bov,
                float* __restrict__ out)
{
    const int b   = blockIdx.x;
    const int tid = threadIdx.x;   // 0..767
    const int grp = tid >> 8;      // pipeline stage 0,1,2 (layer)
    const int lt  = tid & 255;     // 0..255 within group
    const int cg  = lt >> 3;       // col-group 0..31 (2 units x 4 gates)
    const int kg  = lt & 7;        // k-group 0..7 (16 k each; 0-3 in, 4-7 rec)
    const int up  = kg & 1;        // unit parity this lane activates
    const int myu = 2 * cg + up;   // my unit

    // LDS: lh[g][p] at (2g+p)*BUF, chunked [4][CH]; x ring linear [RING][64]
    __shared__ __align__(16) float ls[6 * BUF];
    __shared__ __align__(16) float lxr[RING][FEAT];
    __shared__ float lact[UNITS];
    float* const lsb = ls;

    // ---- weights: 8 cols x 16 k as v2f wt[16][4] (col pair = unit even/odd) --
    const float* Wsel = (grp == 0) ? W0 : W1;
    const float* Usel = (grp == 0) ? U0 : U1;
    const float* bsel = (grp == 0) ? b0 : b1;
    const float* Msel = (kg < 4) ? Wsel : Usel;

    v2f wt[16][4];
    float biasv[4];
#pragma unroll
    for (int g = 0; g < 4; ++g) {
        const int colb = (g << 6) + 2 * cg;
#pragma unroll
        for (int k = 0; k < 16; ++k) {
            const int r = (kg & 3) * 16 + k;
            wt[k][g] = (v2f){Msel[r * NCOL + colb], Msel[r * NCOL + colb + 1]};
        }
        biasv[g] = bsel[(g << 6) + myu];
    }

    // zero h buffers (both parities, all 3 layers)
    if (tid < 6 * BUF) lsb[tid] = 0.f;

    // x ring prologue: DMA x(0..PFD-1) into slots 0..PFD-1 (lanes 0..15)
    const float* xbase = x + (size_t)b * SEQT * FEAT;
    if (tid < 16) {
#pragma unroll
        for (int s = 0; s < PFD; ++s)
            gload16(&lxr[s][0], xbase + (size_t)s * FEAT + tid * 4);
    }
    __syncthreads();   // one-time full drain (weights + ring prologue)

    // per-lane operand chunk pointers, both parities
    // in: G0 <- x ring (overridden per tick), G1 <- lh0, G2 <- lh1 ; rec: lh[grp]
    const float* inB0 = (grp == 0) ? lsb : (lsb + (2 * (grp - 1)) * BUF);
    const float* inB1 = inB0 + BUF;
    const float* rcB0 = lsb + (2 * grp) * BUF;
    const float* rcB1 = rcB0 + BUF;
    const int chOff = (kg & 3) * CH;
    const float* opP0 = ((kg < 4) ? inB0 : rcB0) + chOff;
    const float* opP1 = ((kg < 4) ? inB1 : rcB1) + chOff;
    const bool xlane = (grp == 0) && (kg < 4);

    // h write pointers (lanes kg<2 write unit myu)
    float* hwp0 = lsb + (2 * grp) * BUF + CH * (myu >> 4) + (myu & 15);
    float* hwp1 = hwp0 + BUF;

    float c = 0.f;

#define MAC1(V, K)                                                            \
    { v2f s_; s_.x = (V); s_.y = (V);                                         \
      a0 = pk_fma(s_, wt[K][0], a0);                                          \
      a1 = pk_fma(s_, wt[K][1], a1);                                          \
      a2 = pk_fma(s_, wt[K][2], a2);                                          \
      a3 = pk_fma(s_, wt[K][3], a3); }

    for (int tk = 0; tk < SEQT + 2; ++tk) {
        // loader lanes: async DMA x(tk+PFD) -> ring slot (tk+PFD)%RING.
        // stays in flight across ticks (loop barrier never drains vmcnt)
        if (tid < 16) {
            const int tn = tk + PFD;
            if (tn < SEQT)
                gload16(&lxr[tn & (RING - 1)][0],
                        xbase + (size_t)tn * FEAT + tid * 4);
        }

        const int t_ = tk - grp;
        if (t_ >= 0 && t_ < SEQT) {
            const float* op = (tk & 1) ? opP0 : opP1;   // parity (tk&1)^1
            if (xlane) op = &lxr[tk & (RING - 1)][kg * 16];  // G0-FF: x(tk)

            float4 o0 = *(const float4*)(op);
            float4 o1 = *(const float4*)(op + 4);
            float4 o2 = *(const float4*)(op + 8);
            float4 o3 = *(const float4*)(op + 12);

            v2f a0 = (v2f){0.f, 0.f}, a1 = a0, a2 = a0, a3 = a0;
            MAC1(o0.x, 0)  MAC1(o0.y, 1)  MAC1(o0.z, 2)  MAC1(o0.w, 3)
            MAC1(o1.x, 4)  MAC1(o1.y, 5)  MAC1(o1.z, 6)  MAC1(o1.w, 7)
            MAC1(o2.x, 8)  MAC1(o2.y, 9)  MAC1(o2.z, 10) MAC1(o2.w, 11)
            MAC1(o3.x, 12) MAC1(o3.y, 13) MAC1(o3.z, 14) MAC1(o3.w, 15)

            v2f z0 = red8v(a0), z1 = red8v(a1), z2 = red8v(a2), z3 = red8v(a3);
            const float zi = (up ? z0.y : z0.x) + biasv[0];
            const float zf = (up ? z1.y : z1.x) + biasv[1];
            const float zg = (up ? z2.y : z2.x) + biasv[2];
            const float zo = (up ? z3.y : z3.x) + biasv[3];

            const float ig = sig_(zi), fg = sig_(zf);
            const float gg = tanh_(zg), og = sig_(zo);
            c = fg * c + ig * gg;
            const float hn = og * tanh_(c);
            if (kg < 2) *((tk & 1) ? hwp1 : hwp0) = hn;
        }

        // loader wave: ensure x(tk+1)'s DMA (issued PFD-1 ticks ago) landed;
        // satisfied ~5 ticks early in steady state, never blocks
        if ((tid >> 6) == 0)
            asm volatile("s_waitcnt vmcnt(5)" ::: "memory");
        // LDS-only drain + barrier: x DMAs stay in flight across ticks
        asm volatile("s_waitcnt lgkmcnt(0)\n\ts_barrier" ::: "memory");
    }
#undef MAC1

    // ---- dense head on final h2 (lh[2] parity 1, chunked) ----
    const float* h2f = lsb + (2 * 2 + 1) * BUF;
    if (tid < UNITS) {
        float a = bfv[tid];
#pragma unroll
        for (int k = 0; k < UNITS; ++k)
            a += h2f[CH * (k >> 4) + (k & 15)] * Wf[k * 64 + tid];
        lact[tid] = fmaxf(a, 0.f);
    }
    __syncthreads();
    if (tid < OUTD) {
        float a = bov[tid];
#pragma unroll
        for (int k = 0; k < UNITS; ++k) a += lact[k] * Wo[k * OUTD + tid];
        out[b * OUTD + tid] = a;
    }
}

extern "C" void kernel_launch(void* const* d_in, const int* in_sizes, int n_in,
                              void* d_out, int out_size, void* d_ws, size_t ws_size,
                              hipStream_t stream) {
    const float* x   = (const float*)d_in[0];
    const float* W0  = (const float*)d_in[1];
    const float* U0  = (const float*)d_in[2];
    const float* b0  = (const float*)d_in[3];
    const float* W1  = (const float*)d_in[4];
    const float* U1  = (const float*)d_in[5];
    const float* b1  = (const float*)d_in[6];
    const float* Wf  = (const float*)d_in[7];
    const float* bfv = (const float*)d_in[8];
    const float* Wo  = (const float*)d_in[9];
    const float* bov = (const float*)d_in[10];
    float* out = (float*)d_out;

    lstm3_ring<<<BATCHN, 768, 0, stream>>>(x, W0, U0, b0, W1, U1, b1,
                                           Wf, bfv, Wo, bov, out);
}